// Round 1
// baseline (678.113 us; speedup 1.0000x reference)
//
#include <hip/hip_runtime.h>
#include <hip/hip_bf16.h>
#include <stdint.h>

// Problem constants (QSGDLinear): out = x @ W^T
//   x: (2,1024,4096) fp32 -> M=2048, K=4096
//   ternary: (16384,4096) int32 in {-1,0,1} -> N=16384
//   scales: (16384*4096/128,) fp32, group = contiguous 128 along K of one row
#define M_ROWS 2048
#define IN_F   4096
#define OUT_F  16384

#define BM 128
#define BN 128
#define BK 64

typedef __attribute__((ext_vector_type(8))) short short8;   // 8 bf16 = 4 VGPRs
typedef __attribute__((ext_vector_type(4))) float floatx4;  // MFMA acc

__device__ __forceinline__ unsigned short f32_to_bf16_rne(float f) {
    union { float f; uint32_t u; } v; v.f = f;
    uint32_t u = v.u;
    return (unsigned short)((u + 0x7FFFu + ((u >> 16) & 1u)) >> 16);
}

// ---- pass 1: x fp32 -> bf16 (8 elems/thread) ----
__global__ __launch_bounds__(256) void convert_x_kernel(
        const float* __restrict__ x, unsigned short* __restrict__ xb) {
    int t = blockIdx.x * 256 + threadIdx.x;
    const float4* p = (const float4*)(x + (size_t)t * 8);
    float4 a = p[0];
    float4 b = p[1];
    short8 o;
    o[0] = (short)f32_to_bf16_rne(a.x);
    o[1] = (short)f32_to_bf16_rne(a.y);
    o[2] = (short)f32_to_bf16_rne(a.z);
    o[3] = (short)f32_to_bf16_rne(a.w);
    o[4] = (short)f32_to_bf16_rne(b.x);
    o[5] = (short)f32_to_bf16_rne(b.y);
    o[6] = (short)f32_to_bf16_rne(b.z);
    o[7] = (short)f32_to_bf16_rne(b.w);
    *(short8*)(xb + (size_t)t * 8) = o;
}

// ---- pass 2: W = ternary * scale -> bf16 (8 elems/thread, all same group) ----
__global__ __launch_bounds__(256) void dequant_w_kernel(
        const int* __restrict__ tern, const float* __restrict__ scales,
        unsigned short* __restrict__ wb) {
    int g = blockIdx.x * 256 + threadIdx.x;          // 8 elems per thread
    float s = scales[g >> 4];                        // (g*8)/128
    const int4* p = (const int4*)(tern + (size_t)g * 8);
    int4 a = p[0];
    int4 b = p[1];
    short8 o;
    o[0] = (short)f32_to_bf16_rne((float)a.x * s);
    o[1] = (short)f32_to_bf16_rne((float)a.y * s);
    o[2] = (short)f32_to_bf16_rne((float)a.z * s);
    o[3] = (short)f32_to_bf16_rne((float)a.w * s);
    o[4] = (short)f32_to_bf16_rne((float)b.x * s);
    o[5] = (short)f32_to_bf16_rne((float)b.y * s);
    o[6] = (short)f32_to_bf16_rne((float)b.z * s);
    o[7] = (short)f32_to_bf16_rne((float)b.w * s);
    *(short8*)(wb + (size_t)g * 8) = o;
}

// ---- pass 3: C[M,N] = A[M,K] * B[N,K]^T, bf16 in / fp32 out (m97 structure) ----
// Block = 256 threads = 4 waves in 2x2; each wave computes 64x64 via 4x4
// 16x16x32 bf16 MFMAs. LDS tiles staged with global_load_lds width=16.
// XOR swizzle: LDS slot (row, j) holds global k-chunk (j ^ (row&7)) so the
// fragment ds_read_b128 spreads over all 32 banks (2-way aliasing = free).
__global__ __launch_bounds__(256, 3) void gemm_bt_kernel(
        const unsigned short* __restrict__ A,   // [M_ROWS][IN_F] bf16 bits
        const unsigned short* __restrict__ B,   // [OUT_F][IN_F] bf16 bits
        float* __restrict__ C) {                // [M_ROWS][OUT_F] fp32
    __shared__ unsigned short As[BM * BK];      // 16 KB
    __shared__ unsigned short Bs[BN * BK];      // 16 KB

    const int tid  = threadIdx.x;
    const int lane = tid & 63;
    const int quad = lane >> 4;        // 0..3
    const int frow = lane & 15;        // fragment row within 16-tile
    const int r7   = frow & 7;
    const int w    = tid >> 6;         // wave 0..3
    const int wm   = (w & 1) * 64;
    const int wn   = (w >> 1) * 64;

    const int bm = blockIdx.x * BM;    // m fastest -> 16 consecutive blocks share a B tile
    const int bn = blockIdx.y * BN;

    floatx4 acc[4][4] = {};

    // Precompute LDS fragment element-offsets (constant over kt).
    int a_off[2][4], b_off[2][4];
#pragma unroll
    for (int ks = 0; ks < 2; ++ks) {
        const int j = ks * 4 + quad;            // global k-chunk 0..7
        const int sw = (j ^ r7) * 8;            // swizzled chunk offset in elems
#pragma unroll
        for (int t2 = 0; t2 < 4; ++t2) {
            a_off[ks][t2] = (wm + t2 * 16 + frow) * BK + sw;
            b_off[ks][t2] = (wn + t2 * 16 + frow) * BK + sw;
        }
    }

    for (int kt = 0; kt < IN_F; kt += BK) {
        __syncthreads();
        // stage 32 KB: 2048 chunks of 16 B; 8 global_load_lds per thread
#pragma unroll
        for (int i = 0; i < 4; ++i) {
            const int c    = 256 * i + tid;       // chunk id (per lane)
            const int crow = c >> 3;              // tile row 0..127
            const int jg   = (c & 7) ^ (crow & 7);// swizzled global k-chunk
            const int ub   = (256 * i + (tid & 192)) * 8; // wave-uniform LDS base (elems)
            const unsigned short* ga =
                A + (size_t)(bm + crow) * IN_F + kt + jg * 8;
            const unsigned short* gb =
                B + (size_t)(bn + crow) * IN_F + kt + jg * 8;
            __builtin_amdgcn_global_load_lds(
                (const __attribute__((address_space(1))) void*)ga,
                (__attribute__((address_space(3))) void*)(As + ub), 16, 0, 0);
            __builtin_amdgcn_global_load_lds(
                (const __attribute__((address_space(1))) void*)gb,
                (__attribute__((address_space(3))) void*)(Bs + ub), 16, 0, 0);
        }
        __syncthreads();
        // compute: 2 k-steps of 16 MFMAs
#pragma unroll
        for (int ks = 0; ks < 2; ++ks) {
            short8 af[4], bf[4];
#pragma unroll
            for (int t2 = 0; t2 < 4; ++t2) {
                af[t2] = *(const short8*)(As + a_off[ks][t2]);
                bf[t2] = *(const short8*)(Bs + b_off[ks][t2]);
            }
#pragma unroll
            for (int mt = 0; mt < 4; ++mt)
#pragma unroll
                for (int nt = 0; nt < 4; ++nt)
                    acc[mt][nt] = __builtin_amdgcn_mfma_f32_16x16x32_bf16(
                        af[mt], bf[nt], acc[mt][nt], 0, 0, 0);
        }
    }

    // epilogue: C/D layout col = lane&15, row = quad*4 + reg  [m89/m91]
    const int row0 = bm + wm + quad * 4;
    const int col0 = bn + wn + frow;
#pragma unroll
    for (int mt = 0; mt < 4; ++mt) {
#pragma unroll
        for (int nt = 0; nt < 4; ++nt) {
            float* cp = C + (size_t)(row0 + mt * 16) * OUT_F + (col0 + nt * 16);
#pragma unroll
            for (int r = 0; r < 4; ++r)
                cp[(size_t)r * OUT_F] = acc[mt][nt][r];
        }
    }
}

extern "C" void kernel_launch(void* const* d_in, const int* in_sizes, int n_in,
                              void* d_out, int out_size, void* d_ws, size_t ws_size,
                              hipStream_t stream) {
    const float* x     = (const float*)d_in[0];
    const int*   tern  = (const int*)d_in[1];
    const float* scal  = (const float*)d_in[2];
    float*       out   = (float*)d_out;

    // workspace: x_bf16 (16 MB) then w_bf16 (128 MB)
    unsigned short* xb = (unsigned short*)d_ws;
    unsigned short* wb = xb + (size_t)M_ROWS * IN_F;

    convert_x_kernel<<<(M_ROWS * IN_F / 8) / 256, 256, 0, stream>>>(x, xb);
    dequant_w_kernel<<<((size_t)OUT_F * IN_F / 8) / 256, 256, 0, stream>>>(tern, scal, wb);
    gemm_bt_kernel<<<dim3(M_ROWS / BM, OUT_F / BN), 256, 0, stream>>>(xb, wb, out);
}